// Round 6
// baseline (321.594 us; speedup 1.0000x reference)
//
#include <hip/hip_runtime.h>

constexpr int N_SRC = 100000;
constexpr int N_DST = 100000;
constexpr int E     = 1600000;
constexpr int D     = 64;
constexpr float LN_EPS = 1e-5f;

constexpr int NCHUNK = 256;            // edge chunks
constexpr int CHUNK  = E / NCHUNK;     // 6250 edges per chunk (exact)
constexpr int BROWS  = 128;            // dst rows per bucket
constexpr int NBK    = (N_DST + BROWS - 1) / BROWS;   // 782 buckets
constexpr int MAXB   = 4096;           // per-bucket edge cap (mean 2046)

typedef __attribute__((ext_vector_type(8))) short bf16x8;
typedef __attribute__((ext_vector_type(4))) float f32x4;

__device__ inline unsigned short bfh(float x) {
    union { float f; unsigned u; } c; c.f = x; return (unsigned short)(c.u >> 16);  // truncate
}
__device__ inline float bff(unsigned short b) {
    union { unsigned u; float f; } c; c.u = (unsigned)b << 16; return c.f;
}
__device__ inline unsigned short bfrne(float x) {
    union { float f; unsigned u; } c; c.f = x;
    unsigned u = c.u + (0x7FFFu + ((c.u >> 16) & 1u));
    return (unsigned short)(u >> 16);
}

// ---------------------------------------------------------------------------
// k_film (MFMA): wave = 64 rows (4 M-tiles of 16). A = feat (split bf16 hi/lo),
// B = [Ww | gamma | beta] columns in 4 triplets of 16. 3 MFMA per product pair
// (hi*hi + hi*lo + lo*hi) ~ f32 accuracy. Fused relu(g*m+b), bf16-RNE store.
// A layout: row=lane&15, k=(lane>>4)*8+j. B: col=lane&15, k=(lane>>4)*8+j.
// C/D: col=lane&15, row=(lane>>4)*4+reg  [verified m89].
// ---------------------------------------------------------------------------
__global__ __launch_bounds__(256) void k_film(const float* __restrict__ feat,
                                              const float* __restrict__ Ww,   // [64][64]
                                              const float* __restrict__ Fw,   // [64][128]
                                              unsigned short* __restrict__ msgb) {
    const int lane = threadIdx.x & 63;
    const int wid  = threadIdx.x >> 6;
    const int w    = blockIdx.x * 4 + wid;     // wave id
    const int m    = lane & 15;
    const int kg   = lane >> 4;
    const int mrow0 = w * 64;

    // A fragments: 4 mtiles x 2 ksteps, hi/lo
    bf16x8 ahi[4][2], alo[4][2];
#pragma unroll
    for (int mt = 0; mt < 4; ++mt) {
        const int rbase = mrow0 + mt * 16 + m;
        const int r = (rbase < N_SRC) ? rbase : 0;
#pragma unroll
        for (int ks = 0; ks < 2; ++ks) {
            const float* p = feat + (size_t)r * 64 + ks * 32 + kg * 8;
            const float4 x0 = *reinterpret_cast<const float4*>(p);
            const float4 x1 = *reinterpret_cast<const float4*>(p + 4);
            const float a[8] = {x0.x, x0.y, x0.z, x0.w, x1.x, x1.y, x1.z, x1.w};
            bf16x8 h, l;
#pragma unroll
            for (int j = 0; j < 8; ++j) {
                const unsigned short hb = bfh(a[j]);
                h[j] = (short)hb;
                l[j] = (short)bfh(a[j] - bff(hb));
            }
            ahi[mt][ks] = h; alo[mt][ks] = l;
        }
    }

    const f32x4 zero = {0.f, 0.f, 0.f, 0.f};

#pragma unroll
    for (int t = 0; t < 4; ++t) {              // (msg, gamma, beta) column triplet
        f32x4 am[4], ag[4], ab[4];
#pragma unroll
        for (int i = 0; i < 4; ++i) { am[i] = zero; ag[i] = zero; ab[i] = zero; }

#pragma unroll
        for (int ks = 0; ks < 2; ++ks) {
            bf16x8 wmh, wml, wgh, wgl, wbh, wbl;
#pragma unroll
            for (int j = 0; j < 8; ++j) {
                const int k = ks * 32 + kg * 8 + j;
                const int n = t * 16 + m;
                const float vm = Ww[k * 64 + n];
                const float vg = Fw[k * 128 + n];
                const float vb = Fw[k * 128 + 64 + n];
                unsigned short hb;
                hb = bfh(vm); wmh[j] = (short)hb; wml[j] = (short)bfh(vm - bff(hb));
                hb = bfh(vg); wgh[j] = (short)hb; wgl[j] = (short)bfh(vg - bff(hb));
                hb = bfh(vb); wbh[j] = (short)hb; wbl[j] = (short)bfh(vb - bff(hb));
            }
#pragma unroll
            for (int mt = 0; mt < 4; ++mt) {
                am[mt] = __builtin_amdgcn_mfma_f32_16x16x32_bf16(ahi[mt][ks], wmh, am[mt], 0, 0, 0);
                am[mt] = __builtin_amdgcn_mfma_f32_16x16x32_bf16(ahi[mt][ks], wml, am[mt], 0, 0, 0);
                am[mt] = __builtin_amdgcn_mfma_f32_16x16x32_bf16(alo[mt][ks], wmh, am[mt], 0, 0, 0);
                ag[mt] = __builtin_amdgcn_mfma_f32_16x16x32_bf16(ahi[mt][ks], wgh, ag[mt], 0, 0, 0);
                ag[mt] = __builtin_amdgcn_mfma_f32_16x16x32_bf16(ahi[mt][ks], wgl, ag[mt], 0, 0, 0);
                ag[mt] = __builtin_amdgcn_mfma_f32_16x16x32_bf16(alo[mt][ks], wgh, ag[mt], 0, 0, 0);
                ab[mt] = __builtin_amdgcn_mfma_f32_16x16x32_bf16(ahi[mt][ks], wbh, ab[mt], 0, 0, 0);
                ab[mt] = __builtin_amdgcn_mfma_f32_16x16x32_bf16(ahi[mt][ks], wbl, ab[mt], 0, 0, 0);
                ab[mt] = __builtin_amdgcn_mfma_f32_16x16x32_bf16(alo[mt][ks], wbh, ab[mt], 0, 0, 0);
            }
        }

        // epilogue: relu(gamma*msg + beta) -> bf16 store
#pragma unroll
        for (int mt = 0; mt < 4; ++mt) {
            const int rb = mrow0 + mt * 16;
            if (rb < N_SRC) {
#pragma unroll
                for (int r4 = 0; r4 < 4; ++r4) {
                    const int row = rb + kg * 4 + r4;
                    const float o = fmaxf(ag[mt][r4] * am[mt][r4] + ab[mt][r4], 0.f);
                    msgb[(size_t)row * 64 + t * 16 + m] = bfrne(o);
                }
            }
        }
    }
}

// ---------------------------------------------------------------------------
// Bucketed counting sort, all atomics in LDS (unchanged from R5).
// ---------------------------------------------------------------------------
__global__ __launch_bounds__(256) void k_hist1(const int* __restrict__ edst,
                                               int* __restrict__ H) {   // H[k][c]
    __shared__ int hl[NBK];
    for (int i = threadIdx.x; i < NBK; i += 256) hl[i] = 0;
    __syncthreads();
    const int c = blockIdx.x;
    const int e0 = c * CHUNK;
    for (int e = e0 + threadIdx.x; e < e0 + CHUNK; e += 256)
        atomicAdd(&hl[edst[e] >> 7], 1);
    __syncthreads();
    for (int i = threadIdx.x; i < NBK; i += 256) H[i * NCHUNK + c] = hl[i];
}

__global__ __launch_bounds__(256) void k_scanH(int* __restrict__ H,
                                               int* __restrict__ bstart) {
    const int k = blockIdx.x;
    const int c = threadIdx.x;
    const int lane = c & 63;
    const int wid = c >> 6;
    const int v = H[k * NCHUNK + c];
    int x = v;
#pragma unroll
    for (int o = 1; o < 64; o <<= 1) { int y = __shfl_up(x, o); if (lane >= o) x += y; }
    __shared__ int wsum[4];
    if (lane == 63) wsum[wid] = x;
    __syncthreads();
    int add = 0;
    for (int w = 0; w < wid; ++w) add += wsum[w];
    const int incl = x + add;
    H[k * NCHUNK + c] = incl - v;
    if (c == 255) bstart[k] = incl;
}

__global__ __launch_bounds__(64) void k_h3(int* __restrict__ bstart) {
    const int lane = threadIdx.x;
    int running = 0;
    for (int b = 0; b < NBK; b += 64) {
        const int idx = b + lane;
        const int v = (idx < NBK) ? bstart[idx] : 0;
        int x = v;
#pragma unroll
        for (int o = 1; o < 64; o <<= 1) { int y = __shfl_up(x, o); if (lane >= o) x += y; }
        if (idx < NBK) bstart[idx] = running + x - v;
        running += __shfl(x, 63);
    }
    if (lane == 0) bstart[NBK] = E;
}

__global__ __launch_bounds__(256) void k_pairs(const int* __restrict__ esrc,
                                               const int* __restrict__ edst,
                                               const int* __restrict__ H,      // exclusive
                                               const int* __restrict__ bstart,
                                               unsigned* __restrict__ pairs) {
    __shared__ int curs[NBK];
    const int c = blockIdx.x;
    for (int i = threadIdx.x; i < NBK; i += 256) curs[i] = bstart[i] + H[i * NCHUNK + c];
    __syncthreads();
    const int e0 = c * CHUNK;
    for (int e = e0 + threadIdx.x; e < e0 + CHUNK; e += 256) {
        const int d = edst[e];
        const int s = esrc[e];
        const int k = d >> 7;
        const int pos = atomicAdd(&curs[k], 1);
        pairs[pos] = ((unsigned)(d & 127) << 24) | (unsigned)s;
    }
}

// ---------------------------------------------------------------------------
// k_reduce2: as R5 but gathers bf16 msg (128B/row instead of 256B).
// ---------------------------------------------------------------------------
__global__ __launch_bounds__(256) void k_reduce2(const unsigned short* __restrict__ msgb,
                                                 const unsigned* __restrict__ pairs,
                                                 const int* __restrict__ bstart,
                                                 const float* __restrict__ sc,
                                                 const float* __restrict__ bi,
                                                 float* __restrict__ out) {
    __shared__ int srcs[MAXB];      // 16 KB row-sorted src ids
    __shared__ int cnt[BROWS];
    __shared__ int off[BROWS];
    __shared__ int cur[BROWS];

    const int k = blockIdx.x;
    const int tid = threadIdx.x;
    const int lane = tid & 63;
    const int wid = tid >> 6;
    const int s0 = bstart[k];
    const int s1 = bstart[k + 1];

    for (int i = tid; i < BROWS; i += 256) cnt[i] = 0;
    __syncthreads();

    for (int i = s0 + tid; i < s1; i += 256) atomicAdd(&cnt[pairs[i] >> 24], 1);
    __syncthreads();

    if (tid < 64) {
        const int a = cnt[lane];
        const int b = cnt[64 + lane];
        int xa = a, xb = b;
#pragma unroll
        for (int o = 1; o < 64; o <<= 1) {
            int ya = __shfl_up(xa, o); if (lane >= o) xa += ya;
            int yb = __shfl_up(xb, o); if (lane >= o) xb += yb;
        }
        const int tot_a = __shfl(xa, 63);
        off[lane]      = xa - a;
        off[64 + lane] = tot_a + xb - b;
        cur[lane]      = off[lane];
        cur[64 + lane] = off[64 + lane];
    }
    __syncthreads();

    for (int i = s0 + tid; i < s1; i += 256) {
        const unsigned p = pairs[i];
        const int pos = atomicAdd(&cur[p >> 24], 1);
        if (pos < MAXB) srcs[pos] = (int)(p & 0x1FFFFu);
    }
    __syncthreads();

    for (int r = wid; r < BROWS; r += 4) {
        const int dst = k * BROWS + r;
        if (dst >= N_DST) break;
        const int rn = cnt[r];
        const int ro = off[r];

        float a = 0.f;
        for (int b0 = 0; b0 < rn; b0 += 64) {
            const int m = min(64, rn - b0);
            const int id = (lane < m) ? srcs[ro + b0 + lane] : 0;
#pragma unroll
            for (int i = 0; i < 64; i += 8) {
                if (i >= m) break;                      // wave-uniform
                float v[8];
#pragma unroll
                for (int j = 0; j < 8; ++j) {
                    const int sj = __builtin_amdgcn_readlane(id, i + j);
                    const bool ok = (i + j) < m;        // wave-uniform
                    const unsigned short xb = msgb[(size_t)(ok ? sj : 0) * D + lane];
                    v[j] = ok ? bff(xb) : 0.f;
                }
                a += ((v[0] + v[1]) + (v[2] + v[3])) + ((v[4] + v[5]) + (v[6] + v[7]));
            }
        }

        float s = a;
#pragma unroll
        for (int o = 32; o > 0; o >>= 1) s += __shfl_xor(s, o);
        const float mu = s * (1.0f / D);
        const float dv = a - mu;
        float s2 = dv * dv;
#pragma unroll
        for (int o = 32; o > 0; o >>= 1) s2 += __shfl_xor(s2, o);
        const float var = s2 * (1.0f / D);
        out[(size_t)dst * D + lane] = dv * rsqrtf(var + LN_EPS) * sc[lane] + bi[lane];
    }
}

// ---------------------------------------------------------------------------
extern "C" void kernel_launch(void* const* d_in, const int* in_sizes, int n_in,
                              void* d_out, int out_size, void* d_ws, size_t ws_size,
                              hipStream_t stream) {
    const float* feat = (const float*)d_in[0];
    const int*   esrc = (const int*)d_in[1];
    const int*   edst = (const int*)d_in[2];
    const float* Ww   = (const float*)d_in[3];
    const float* Fw   = (const float*)d_in[4];
    const float* sc   = (const float*)d_in[5];
    const float* bi   = (const float*)d_in[6];
    float* out = (float*)d_out;

    char* ws = (char*)d_ws;
    unsigned short* msgb = (unsigned short*)(ws);            // 12.8 MB bf16 msg
    unsigned* pairs  = (unsigned*)(ws + 26u * 1024 * 1024);  // 6.4 MB
    int*      H      = (int*)(ws + 33u * 1024 * 1024);       // 800 KB
    int*      bstart = (int*)(ws + 34u * 1024 * 1024);       // 783*4

    // 100000 rows = 6250 M-tiles = 1562.5 waves of 4 tiles -> 391 blocks
    k_film  <<<391, 256, 0, stream>>>(feat, Ww, Fw, msgb);
    k_hist1 <<<NCHUNK, 256, 0, stream>>>(edst, H);
    k_scanH <<<NBK, 256, 0, stream>>>(H, bstart);
    k_h3    <<<1, 64, 0, stream>>>(bstart);
    k_pairs <<<NCHUNK, 256, 0, stream>>>(esrc, edst, H, bstart, pairs);
    k_reduce2<<<NBK, 256, 0, stream>>>(msgb, pairs, bstart, sc, bi, out);
}

// Round 10
// 232.776 us; speedup vs baseline: 1.3816x; 1.3816x over previous
//
#include <hip/hip_runtime.h>

constexpr int N_SRC = 100000;
constexpr int N_DST = 100000;
constexpr int E     = 1600000;
constexpr int D     = 64;
constexpr float LN_EPS = 1e-5f;

constexpr int NCHUNK = 512;            // edge chunks
constexpr int CHUNK  = E / NCHUNK;     // 3125 edges per chunk (exact)
constexpr int BROWS  = 128;            // dst rows per bucket
constexpr int NBK    = (N_DST + BROWS - 1) / BROWS;   // 782 buckets
constexpr int MAXB   = 4096;           // per-bucket edge cap (mean 2046)

typedef __attribute__((ext_vector_type(8))) short bf16x8;
typedef __attribute__((ext_vector_type(4))) float f32x4;

__device__ inline unsigned short bfh(float x) {
    union { float f; unsigned u; } c; c.f = x; return (unsigned short)(c.u >> 16);  // truncate
}
__device__ inline float bff(unsigned short b) {
    union { unsigned u; float f; } c; c.u = (unsigned)b << 16; return c.f;
}
__device__ inline float asf(unsigned u) {
    union { unsigned u; float f; } c; c.u = u; return c.f;
}
__device__ inline unsigned short bfrne(float x) {
    union { float f; unsigned u; } c; c.f = x;
    unsigned u = c.u + (0x7FFFu + ((c.u >> 16) & 1u));
    return (unsigned short)(u >> 16);
}

// ---------------------------------------------------------------------------
// k_film (MFMA): wave = 64 rows (4 M-tiles of 16). A = feat (split bf16 hi/lo),
// B = [Ww | gamma | beta] columns in 4 triplets of 16. 3 MFMA per product pair
// (hi*hi + hi*lo + lo*hi) ~ f32 accuracy. Fused relu(g*m+b), bf16-RNE store.
// ---------------------------------------------------------------------------
__global__ __launch_bounds__(256) void k_film(const float* __restrict__ feat,
                                              const float* __restrict__ Ww,   // [64][64]
                                              const float* __restrict__ Fw,   // [64][128]
                                              unsigned short* __restrict__ msgb) {
    const int lane = threadIdx.x & 63;
    const int wid  = threadIdx.x >> 6;
    const int w    = blockIdx.x * 4 + wid;     // wave id
    const int m    = lane & 15;
    const int kg   = lane >> 4;
    const int mrow0 = w * 64;

    bf16x8 ahi[4][2], alo[4][2];
#pragma unroll
    for (int mt = 0; mt < 4; ++mt) {
        const int rbase = mrow0 + mt * 16 + m;
        const int r = (rbase < N_SRC) ? rbase : 0;
#pragma unroll
        for (int ks = 0; ks < 2; ++ks) {
            const float* p = feat + (size_t)r * 64 + ks * 32 + kg * 8;
            const float4 x0 = *reinterpret_cast<const float4*>(p);
            const float4 x1 = *reinterpret_cast<const float4*>(p + 4);
            const float a[8] = {x0.x, x0.y, x0.z, x0.w, x1.x, x1.y, x1.z, x1.w};
            bf16x8 h, l;
#pragma unroll
            for (int j = 0; j < 8; ++j) {
                const unsigned short hb = bfh(a[j]);
                h[j] = (short)hb;
                l[j] = (short)bfh(a[j] - bff(hb));
            }
            ahi[mt][ks] = h; alo[mt][ks] = l;
        }
    }

    const f32x4 zero = {0.f, 0.f, 0.f, 0.f};

#pragma unroll
    for (int t = 0; t < 4; ++t) {
        f32x4 am[4], ag[4], ab[4];
#pragma unroll
        for (int i = 0; i < 4; ++i) { am[i] = zero; ag[i] = zero; ab[i] = zero; }

#pragma unroll
        for (int ks = 0; ks < 2; ++ks) {
            bf16x8 wmh, wml, wgh, wgl, wbh, wbl;
#pragma unroll
            for (int j = 0; j < 8; ++j) {
                const int k = ks * 32 + kg * 8 + j;
                const int n = t * 16 + m;
                const float vm = Ww[k * 64 + n];
                const float vg = Fw[k * 128 + n];
                const float vb = Fw[k * 128 + 64 + n];
                unsigned short hb;
                hb = bfh(vm); wmh[j] = (short)hb; wml[j] = (short)bfh(vm - bff(hb));
                hb = bfh(vg); wgh[j] = (short)hb; wgl[j] = (short)bfh(vg - bff(hb));
                hb = bfh(vb); wbh[j] = (short)hb; wbl[j] = (short)bfh(vb - bff(hb));
            }
#pragma unroll
            for (int mt = 0; mt < 4; ++mt) {
                am[mt] = __builtin_amdgcn_mfma_f32_16x16x32_bf16(ahi[mt][ks], wmh, am[mt], 0, 0, 0);
                am[mt] = __builtin_amdgcn_mfma_f32_16x16x32_bf16(ahi[mt][ks], wml, am[mt], 0, 0, 0);
                am[mt] = __builtin_amdgcn_mfma_f32_16x16x32_bf16(alo[mt][ks], wmh, am[mt], 0, 0, 0);
                ag[mt] = __builtin_amdgcn_mfma_f32_16x16x32_bf16(ahi[mt][ks], wgh, ag[mt], 0, 0, 0);
                ag[mt] = __builtin_amdgcn_mfma_f32_16x16x32_bf16(ahi[mt][ks], wgl, ag[mt], 0, 0, 0);
                ag[mt] = __builtin_amdgcn_mfma_f32_16x16x32_bf16(alo[mt][ks], wgh, ag[mt], 0, 0, 0);
                ab[mt] = __builtin_amdgcn_mfma_f32_16x16x32_bf16(ahi[mt][ks], wbh, ab[mt], 0, 0, 0);
                ab[mt] = __builtin_amdgcn_mfma_f32_16x16x32_bf16(ahi[mt][ks], wbl, ab[mt], 0, 0, 0);
                ab[mt] = __builtin_amdgcn_mfma_f32_16x16x32_bf16(alo[mt][ks], wbh, ab[mt], 0, 0, 0);
            }
        }

#pragma unroll
        for (int mt = 0; mt < 4; ++mt) {
            const int rb = mrow0 + mt * 16;
            if (rb < N_SRC) {
#pragma unroll
                for (int r4 = 0; r4 < 4; ++r4) {
                    const int row = rb + kg * 4 + r4;
                    const float o = fmaxf(ag[mt][r4] * am[mt][r4] + ab[mt][r4], 0.f);
                    msgb[(size_t)row * 64 + t * 16 + m] = bfrne(o);
                }
            }
        }
    }
}

// ---------------------------------------------------------------------------
// Bucketed counting sort, all atomics in LDS.
// ---------------------------------------------------------------------------
__global__ __launch_bounds__(256) void k_hist1(const int* __restrict__ edst,
                                               int* __restrict__ H) {   // H[k][c]
    __shared__ int hl[NBK];
    for (int i = threadIdx.x; i < NBK; i += 256) hl[i] = 0;
    __syncthreads();
    const int c = blockIdx.x;
    const int e0 = c * CHUNK;
    for (int e = e0 + threadIdx.x; e < e0 + CHUNK; e += 256)
        atomicAdd(&hl[edst[e] >> 7], 1);
    __syncthreads();
    for (int i = threadIdx.x; i < NBK; i += 256) H[i * NCHUNK + c] = hl[i];
}

// one block (512 threads) per bucket: exclusive scan over 512 chunks
__global__ __launch_bounds__(512) void k_scanH(int* __restrict__ H,
                                               int* __restrict__ bstart) {
    const int k = blockIdx.x;
    const int c = threadIdx.x;
    const int lane = c & 63;
    const int wid = c >> 6;
    const int v = H[k * NCHUNK + c];
    int x = v;
#pragma unroll
    for (int o = 1; o < 64; o <<= 1) { int y = __shfl_up(x, o); if (lane >= o) x += y; }
    __shared__ int wsum[8];
    if (lane == 63) wsum[wid] = x;
    __syncthreads();
    int add = 0;
    for (int w = 0; w < wid; ++w) add += wsum[w];
    const int incl = x + add;
    H[k * NCHUNK + c] = incl - v;
    if (c == NCHUNK - 1) bstart[k] = incl;
}

__global__ __launch_bounds__(64) void k_h3(int* __restrict__ bstart) {
    const int lane = threadIdx.x;
    int running = 0;
    for (int b = 0; b < NBK; b += 64) {
        const int idx = b + lane;
        const int v = (idx < NBK) ? bstart[idx] : 0;
        int x = v;
#pragma unroll
        for (int o = 1; o < 64; o <<= 1) { int y = __shfl_up(x, o); if (lane >= o) x += y; }
        if (idx < NBK) bstart[idx] = running + x - v;
        running += __shfl(x, 63);
    }
    if (lane == 0) bstart[NBK] = E;
}

__global__ __launch_bounds__(256) void k_pairs(const int* __restrict__ esrc,
                                               const int* __restrict__ edst,
                                               const int* __restrict__ H,      // exclusive
                                               const int* __restrict__ bstart,
                                               unsigned* __restrict__ pairs) {
    __shared__ int curs[NBK];
    const int c = blockIdx.x;
    for (int i = threadIdx.x; i < NBK; i += 256) curs[i] = bstart[i] + H[i * NCHUNK + c];
    __syncthreads();
    const int e0 = c * CHUNK;
    for (int e = e0 + threadIdx.x; e < e0 + CHUNK; e += 256) {
        const int d = edst[e];
        const int s = esrc[e];
        const int k = d >> 7;
        const int pos = atomicAdd(&curs[k], 1);
        pairs[pos] = ((unsigned)(d & 127) << 24) | (unsigned)s;
    }
}

// ---------------------------------------------------------------------------
// k_reduce2: one block per bucket (128 dst rows).
//  Phase 1: LDS counting sort of src ids by row (int LDS atomics only).
//  Phase 2: wave per dst row; lane = (quarter q, colgroup c): loads uint2
//           (4 bf16 cols) of edge (4j+q) -> 4 edges per gather instruction,
//           dword-granularity (no sub-dword penalty). Quarter partial sums
//           combine via shfl_xor(32/16); fused LN; lanes 0-15 store float4.
// ---------------------------------------------------------------------------
__global__ __launch_bounds__(256) void k_reduce2(const unsigned short* __restrict__ msgb,
                                                 const unsigned* __restrict__ pairs,
                                                 const int* __restrict__ bstart,
                                                 const float* __restrict__ sc,
                                                 const float* __restrict__ bi,
                                                 float* __restrict__ out) {
    __shared__ int srcs[MAXB];      // 16 KB row-sorted src ids
    __shared__ int cnt[BROWS];
    __shared__ int off[BROWS];
    __shared__ int cur[BROWS];

    const int k = blockIdx.x;
    const int tid = threadIdx.x;
    const int lane = tid & 63;
    const int wid = tid >> 6;
    const int s0 = bstart[k];
    const int s1 = bstart[k + 1];

    for (int i = tid; i < BROWS; i += 256) cnt[i] = 0;
    __syncthreads();

    for (int i = s0 + tid; i < s1; i += 256) atomicAdd(&cnt[pairs[i] >> 24], 1);
    __syncthreads();

    if (tid < 64) {
        const int a = cnt[lane];
        const int b = cnt[64 + lane];
        int xa = a, xb = b;
#pragma unroll
        for (int o = 1; o < 64; o <<= 1) {
            int ya = __shfl_up(xa, o); if (lane >= o) xa += ya;
            int yb = __shfl_up(xb, o); if (lane >= o) xb += yb;
        }
        const int tot_a = __shfl(xa, 63);
        off[lane]      = xa - a;
        off[64 + lane] = tot_a + xb - b;
        cur[lane]      = off[lane];
        cur[64 + lane] = off[64 + lane];
    }
    __syncthreads();

    for (int i = s0 + tid; i < s1; i += 256) {
        const unsigned p = pairs[i];
        const int pos = atomicAdd(&cur[p >> 24], 1);
        if (pos < MAXB) srcs[pos] = (int)(p & 0x1FFFFu);
    }
    __syncthreads();

    const int q = lane >> 4;        // quarter-wave: which edge in group of 4
    const int c = lane & 15;        // 4-col group: cols 4c..4c+3

    for (int r = wid; r < BROWS; r += 4) {
        const int dst = k * BROWS + r;
        if (dst >= N_DST) break;
        const int rn = cnt[r];
        const int ro = off[r];

        float ax = 0.f, ay = 0.f, az = 0.f, aw = 0.f;
        for (int b0 = 0; b0 < rn; b0 += 32) {      // 32 edges per iter, 8 loads
            int sj[8]; bool okv[8];
#pragma unroll
            for (int j = 0; j < 8; ++j) {
                const int ei = b0 + 4 * j + q;
                okv[j] = ei < rn;
                sj[j] = srcs[ro + min(ei, rn - 1)];   // 16-lane broadcast read
            }
#pragma unroll
            for (int j = 0; j < 8; ++j) {
                if (b0 + 4 * j >= rn) break;          // wave-uniform early out
                const uint2 v = *reinterpret_cast<const uint2*>(
                    msgb + (size_t)sj[j] * D + c * 4);
                const unsigned msk = okv[j] ? 0xFFFFFFFFu : 0u;
                const unsigned vx = v.x & msk, vy = v.y & msk;
                ax += asf(vx << 16);
                ay += asf(vx & 0xFFFF0000u);
                az += asf(vy << 16);
                aw += asf(vy & 0xFFFF0000u);
            }
        }

        // combine the 4 quarter-wave partial sums
        ax += __shfl_xor(ax, 32); ay += __shfl_xor(ay, 32);
        az += __shfl_xor(az, 32); aw += __shfl_xor(aw, 32);
        ax += __shfl_xor(ax, 16); ay += __shfl_xor(ay, 16);
        az += __shfl_xor(az, 16); aw += __shfl_xor(aw, 16);

        // LayerNorm over 64 cols = 16 lanes x 4 comps
        float s = (ax + ay) + (az + aw);
#pragma unroll
        for (int o = 8; o > 0; o >>= 1) s += __shfl_xor(s, o);
        const float mu = s * (1.0f / D);
        const float dx = ax - mu, dy = ay - mu, dz = az - mu, dw = aw - mu;
        float s2 = (dx * dx + dy * dy) + (dz * dz + dw * dw);
#pragma unroll
        for (int o = 8; o > 0; o >>= 1) s2 += __shfl_xor(s2, o);
        const float rs = rsqrtf(s2 * (1.0f / D) + LN_EPS);

        if (lane < 16) {
            const float4 scv = *reinterpret_cast<const float4*>(sc + c * 4);
            const float4 biv = *reinterpret_cast<const float4*>(bi + c * 4);
            float4 o4;
            o4.x = dx * rs * scv.x + biv.x;
            o4.y = dy * rs * scv.y + biv.y;
            o4.z = dz * rs * scv.z + biv.z;
            o4.w = dw * rs * scv.w + biv.w;
            *reinterpret_cast<float4*>(out + (size_t)dst * D + c * 4) = o4;
        }
    }
}

// ---------------------------------------------------------------------------
extern "C" void kernel_launch(void* const* d_in, const int* in_sizes, int n_in,
                              void* d_out, int out_size, void* d_ws, size_t ws_size,
                              hipStream_t stream) {
    const float* feat = (const float*)d_in[0];
    const int*   esrc = (const int*)d_in[1];
    const int*   edst = (const int*)d_in[2];
    const float* Ww   = (const float*)d_in[3];
    const float* Fw   = (const float*)d_in[4];
    const float* sc   = (const float*)d_in[5];
    const float* bi   = (const float*)d_in[6];
    float* out = (float*)d_out;

    char* ws = (char*)d_ws;
    unsigned short* msgb = (unsigned short*)(ws);            // 12.8 MB bf16 msg
    unsigned* pairs  = (unsigned*)(ws + 26u * 1024 * 1024);  // 6.4 MB
    int*      H      = (int*)(ws + 33u * 1024 * 1024);       // 782*512*4 = 1.6 MB
    int*      bstart = (int*)(ws + 35u * 1024 * 1024);       // 783*4

    k_film  <<<391, 256, 0, stream>>>(feat, Ww, Fw, msgb);
    k_hist1 <<<NCHUNK, 256, 0, stream>>>(edst, H);
    k_scanH <<<NBK, 512, 0, stream>>>(H, bstart);
    k_h3    <<<1, 64, 0, stream>>>(bstart);
    k_pairs <<<NCHUNK, 256, 0, stream>>>(esrc, edst, H, bstart, pairs);
    k_reduce2<<<NBK, 256, 0, stream>>>(msgb, pairs, bstart, sc, bi, out);
}

// Round 11
// 205.595 us; speedup vs baseline: 1.5642x; 1.1322x over previous
//
#include <hip/hip_runtime.h>

constexpr int N_SRC = 100000;
constexpr int N_DST = 100000;
constexpr int E     = 1600000;
constexpr int D     = 64;
constexpr float LN_EPS = 1e-5f;

constexpr int NCHUNK = 512;            // edge chunks
constexpr int CHUNK  = E / NCHUNK;     // 3125 edges per chunk (exact)
constexpr int BROWS  = 128;            // dst rows per bucket
constexpr int NBK    = (N_DST + BROWS - 1) / BROWS;   // 782 buckets
constexpr int MAXB   = 4096;           // per-bucket edge cap (mean 2046)
constexpr int FB     = 72;             // padded k-stride (ushorts) for weight LDS

typedef __attribute__((ext_vector_type(8))) short bf16x8;
typedef __attribute__((ext_vector_type(4))) float f32x4;

__device__ inline unsigned short bfh(float x) {
    union { float f; unsigned u; } c; c.f = x; return (unsigned short)(c.u >> 16);  // truncate
}
__device__ inline float bff(unsigned short b) {
    union { unsigned u; float f; } c; c.u = (unsigned)b << 16; return c.f;
}
__device__ inline float asf(unsigned u) {
    union { unsigned u; float f; } c; c.u = u; return c.f;
}
__device__ inline unsigned short bfrne(float x) {
    union { float f; unsigned u; } c; c.f = x;
    unsigned u = c.u + (0x7FFFu + ((c.u >> 16) & 1u));
    return (unsigned short)(u >> 16);
}

// ---------------------------------------------------------------------------
// k_film v2: block = 128 rows (4 waves x 2 M-tiles). Weights split hi/lo ONCE
// per block into padded LDS ([6][64][FB] ushorts, 144B row stride ->
// conflict-free ds_read_b128 fragments), killing the per-wave re-convert
// (was ~192 VMEM + ~1200 VALU per wave). Inner loop: 6 ds_reads + 18 MFMA
// per (t,ks). 3-term split (hi*hi+hi*lo+lo*hi) ~ f32 accuracy.
// ---------------------------------------------------------------------------
__global__ __launch_bounds__(256) void k_film(const float* __restrict__ feat,
                                              const float* __restrict__ Ww,   // [64][64]
                                              const float* __restrict__ Fw,   // [64][128]
                                              unsigned short* __restrict__ msgb) {
    __shared__ unsigned short wl[6 * 64 * FB];   // 55296 B

    const int tid  = threadIdx.x;
    const int lane = tid & 63;
    const int wid  = tid >> 6;
    const int m    = lane & 15;
    const int kg   = lane >> 4;
    const int mrow0 = (blockIdx.x * 4 + wid) * 32;   // 32 rows per wave

    // ---- A fragments: 2 mtiles x 2 ksteps, hi/lo (per-thread, registers) ----
    bf16x8 ahi[2][2], alo[2][2];
#pragma unroll
    for (int mt = 0; mt < 2; ++mt) {
        const int rbase = mrow0 + mt * 16 + m;
        const int r = (rbase < N_SRC) ? rbase : 0;
#pragma unroll
        for (int ks = 0; ks < 2; ++ks) {
            const float* p = feat + (size_t)r * 64 + ks * 32 + kg * 8;
            const float4 x0 = *reinterpret_cast<const float4*>(p);
            const float4 x1 = *reinterpret_cast<const float4*>(p + 4);
            const float a[8] = {x0.x, x0.y, x0.z, x0.w, x1.x, x1.y, x1.z, x1.w};
            bf16x8 h, l;
#pragma unroll
            for (int j = 0; j < 8; ++j) {
                const unsigned short hb = bfh(a[j]);
                h[j] = (short)hb;
                l[j] = (short)bfh(a[j] - bff(hb));
            }
            ahi[mt][ks] = h; alo[mt][ks] = l;
        }
    }

    // ---- weight split -> LDS, once per block ----
    // 1536 tasks = mu(3) x n(64) x g(8); each: 8 column loads, split, 2x 16B LDS store
    for (int task = tid; task < 1536; task += 256) {
        const int g  = task & 7;
        const int n  = (task >> 3) & 63;
        const int mu = task >> 9;                 // 0=Wm, 1=gamma, 2=beta
        const float* src;
        int stride;
        if (mu == 0)      { src = Ww + n;       stride = 64;  }
        else if (mu == 1) { src = Fw + n;       stride = 128; }
        else              { src = Fw + 64 + n;  stride = 128; }
        bf16x8 h, l;
#pragma unroll
        for (int j = 0; j < 8; ++j) {
            const float v = src[(size_t)(8 * g + j) * stride];
            const unsigned short hb = bfh(v);
            h[j] = (short)hb;
            l[j] = (short)bfh(v - bff(hb));
        }
        *reinterpret_cast<bf16x8*>(&wl[(2 * mu + 0) * 64 * FB + n * FB + g * 8]) = h;
        *reinterpret_cast<bf16x8*>(&wl[(2 * mu + 1) * 64 * FB + n * FB + g * 8]) = l;
    }
    __syncthreads();

    const f32x4 zero = {0.f, 0.f, 0.f, 0.f};

#pragma unroll
    for (int t = 0; t < 4; ++t) {
        f32x4 am[2], ag[2], ab[2];
#pragma unroll
        for (int i = 0; i < 2; ++i) { am[i] = zero; ag[i] = zero; ab[i] = zero; }

#pragma unroll
        for (int ks = 0; ks < 2; ++ks) {
            const int n = t * 16 + m;
            const int koff = ks * 32 + kg * 8;
            const int base = n * FB + koff;
            const bf16x8 wmh = *reinterpret_cast<const bf16x8*>(&wl[0 * 64 * FB + base]);
            const bf16x8 wml = *reinterpret_cast<const bf16x8*>(&wl[1 * 64 * FB + base]);
            const bf16x8 wgh = *reinterpret_cast<const bf16x8*>(&wl[2 * 64 * FB + base]);
            const bf16x8 wgl = *reinterpret_cast<const bf16x8*>(&wl[3 * 64 * FB + base]);
            const bf16x8 wbh = *reinterpret_cast<const bf16x8*>(&wl[4 * 64 * FB + base]);
            const bf16x8 wbl = *reinterpret_cast<const bf16x8*>(&wl[5 * 64 * FB + base]);
#pragma unroll
            for (int mt = 0; mt < 2; ++mt) {
                am[mt] = __builtin_amdgcn_mfma_f32_16x16x32_bf16(ahi[mt][ks], wmh, am[mt], 0, 0, 0);
                am[mt] = __builtin_amdgcn_mfma_f32_16x16x32_bf16(ahi[mt][ks], wml, am[mt], 0, 0, 0);
                am[mt] = __builtin_amdgcn_mfma_f32_16x16x32_bf16(alo[mt][ks], wmh, am[mt], 0, 0, 0);
                ag[mt] = __builtin_amdgcn_mfma_f32_16x16x32_bf16(ahi[mt][ks], wgh, ag[mt], 0, 0, 0);
                ag[mt] = __builtin_amdgcn_mfma_f32_16x16x32_bf16(ahi[mt][ks], wgl, ag[mt], 0, 0, 0);
                ag[mt] = __builtin_amdgcn_mfma_f32_16x16x32_bf16(alo[mt][ks], wgh, ag[mt], 0, 0, 0);
                ab[mt] = __builtin_amdgcn_mfma_f32_16x16x32_bf16(ahi[mt][ks], wbh, ab[mt], 0, 0, 0);
                ab[mt] = __builtin_amdgcn_mfma_f32_16x16x32_bf16(ahi[mt][ks], wbl, ab[mt], 0, 0, 0);
                ab[mt] = __builtin_amdgcn_mfma_f32_16x16x32_bf16(alo[mt][ks], wbh, ab[mt], 0, 0, 0);
            }
        }

#pragma unroll
        for (int mt = 0; mt < 2; ++mt) {
            const int rb = mrow0 + mt * 16;
            if (rb < N_SRC) {      // N_SRC % 16 == 0: mtile all-or-nothing
#pragma unroll
                for (int r4 = 0; r4 < 4; ++r4) {
                    const int row = rb + kg * 4 + r4;
                    const float o = fmaxf(ag[mt][r4] * am[mt][r4] + ab[mt][r4], 0.f);
                    msgb[(size_t)row * 64 + t * 16 + m] = bfrne(o);
                }
            }
        }
    }
}

// ---------------------------------------------------------------------------
// Bucketed counting sort, all atomics in LDS.
// ---------------------------------------------------------------------------
__global__ __launch_bounds__(256) void k_hist1(const int* __restrict__ edst,
                                               int* __restrict__ H) {   // H[k][c]
    __shared__ int hl[NBK];
    for (int i = threadIdx.x; i < NBK; i += 256) hl[i] = 0;
    __syncthreads();
    const int c = blockIdx.x;
    const int e0 = c * CHUNK;
    for (int e = e0 + threadIdx.x; e < e0 + CHUNK; e += 256)
        atomicAdd(&hl[edst[e] >> 7], 1);
    __syncthreads();
    for (int i = threadIdx.x; i < NBK; i += 256) H[i * NCHUNK + c] = hl[i];
}

// one block (512 threads) per bucket: exclusive scan over 512 chunks
__global__ __launch_bounds__(512) void k_scanH(int* __restrict__ H,
                                               int* __restrict__ bstart) {
    const int k = blockIdx.x;
    const int c = threadIdx.x;
    const int lane = c & 63;
    const int wid = c >> 6;
    const int v = H[k * NCHUNK + c];
    int x = v;
#pragma unroll
    for (int o = 1; o < 64; o <<= 1) { int y = __shfl_up(x, o); if (lane >= o) x += y; }
    __shared__ int wsum[8];
    if (lane == 63) wsum[wid] = x;
    __syncthreads();
    int add = 0;
    for (int w = 0; w < wid; ++w) add += wsum[w];
    const int incl = x + add;
    H[k * NCHUNK + c] = incl - v;
    if (c == NCHUNK - 1) bstart[k] = incl;
}

__global__ __launch_bounds__(64) void k_h3(int* __restrict__ bstart) {
    const int lane = threadIdx.x;
    int running = 0;
    for (int b = 0; b < NBK; b += 64) {
        const int idx = b + lane;
        const int v = (idx < NBK) ? bstart[idx] : 0;
        int x = v;
#pragma unroll
        for (int o = 1; o < 64; o <<= 1) { int y = __shfl_up(x, o); if (lane >= o) x += y; }
        if (idx < NBK) bstart[idx] = running + x - v;
        running += __shfl(x, 63);
    }
    if (lane == 0) bstart[NBK] = E;
}

__global__ __launch_bounds__(256) void k_pairs(const int* __restrict__ esrc,
                                               const int* __restrict__ edst,
                                               const int* __restrict__ H,      // exclusive
                                               const int* __restrict__ bstart,
                                               unsigned* __restrict__ pairs) {
    __shared__ int curs[NBK];
    const int c = blockIdx.x;
    for (int i = threadIdx.x; i < NBK; i += 256) curs[i] = bstart[i] + H[i * NCHUNK + c];
    __syncthreads();
    const int e0 = c * CHUNK;
    for (int e = e0 + threadIdx.x; e < e0 + CHUNK; e += 256) {
        const int d = edst[e];
        const int s = esrc[e];
        const int k = d >> 7;
        const int pos = atomicAdd(&curs[k], 1);
        pairs[pos] = ((unsigned)(d & 127) << 24) | (unsigned)s;
    }
}

// ---------------------------------------------------------------------------
// k_reduce2 v2: 512 threads (8 waves) per bucket block -> ~24 waves/CU
// (was 12): doubles latency-hiding for the per-row serial chains.
//  Phase 1: LDS counting sort of src ids by row (int LDS atomics only).
//  Phase 2: wave per dst row, 16 rows/wave; uint2 (4 bf16 cols) per lane,
//           4 edges per wave-gather; shfl_xor merge; fused LN; float4 store.
// ---------------------------------------------------------------------------
__global__ __launch_bounds__(512) void k_reduce2(const unsigned short* __restrict__ msgb,
                                                 const unsigned* __restrict__ pairs,
                                                 const int* __restrict__ bstart,
                                                 const float* __restrict__ sc,
                                                 const float* __restrict__ bi,
                                                 float* __restrict__ out) {
    __shared__ int srcs[MAXB];      // 16 KB row-sorted src ids
    __shared__ int cnt[BROWS];
    __shared__ int off[BROWS];
    __shared__ int cur[BROWS];

    const int k = blockIdx.x;
    const int tid = threadIdx.x;
    const int lane = tid & 63;
    const int wid = tid >> 6;
    const int s0 = bstart[k];
    const int s1 = bstart[k + 1];

    for (int i = tid; i < BROWS; i += 512) cnt[i] = 0;
    __syncthreads();

    for (int i = s0 + tid; i < s1; i += 512) atomicAdd(&cnt[pairs[i] >> 24], 1);
    __syncthreads();

    if (tid < 64) {
        const int a = cnt[lane];
        const int b = cnt[64 + lane];
        int xa = a, xb = b;
#pragma unroll
        for (int o = 1; o < 64; o <<= 1) {
            int ya = __shfl_up(xa, o); if (lane >= o) xa += ya;
            int yb = __shfl_up(xb, o); if (lane >= o) xb += yb;
        }
        const int tot_a = __shfl(xa, 63);
        off[lane]      = xa - a;
        off[64 + lane] = tot_a + xb - b;
        cur[lane]      = off[lane];
        cur[64 + lane] = off[64 + lane];
    }
    __syncthreads();

    for (int i = s0 + tid; i < s1; i += 512) {
        const unsigned p = pairs[i];
        const int pos = atomicAdd(&cur[p >> 24], 1);
        if (pos < MAXB) srcs[pos] = (int)(p & 0x1FFFFu);
    }
    __syncthreads();

    const int q = lane >> 4;        // quarter-wave: which edge in group of 4
    const int c = lane & 15;        // 4-col group: cols 4c..4c+3

    for (int r = wid; r < BROWS; r += 8) {
        const int dst = k * BROWS + r;
        if (dst >= N_DST) break;
        const int rn = cnt[r];
        const int ro = off[r];

        float ax = 0.f, ay = 0.f, az = 0.f, aw = 0.f;
        for (int b0 = 0; b0 < rn; b0 += 32) {      // 32 edges per iter, 8 loads
            int sj[8]; bool okv[8];
#pragma unroll
            for (int j = 0; j < 8; ++j) {
                const int ei = b0 + 4 * j + q;
                okv[j] = ei < rn;
                sj[j] = srcs[ro + min(ei, rn - 1)];   // 16-lane broadcast read
            }
#pragma unroll
            for (int j = 0; j < 8; ++j) {
                if (b0 + 4 * j >= rn) break;          // wave-uniform early out
                const uint2 v = *reinterpret_cast<const uint2*>(
                    msgb + (size_t)sj[j] * D + c * 4);
                const unsigned msk = okv[j] ? 0xFFFFFFFFu : 0u;
                const unsigned vx = v.x & msk, vy = v.y & msk;
                ax += asf(vx << 16);
                ay += asf(vx & 0xFFFF0000u);
                az += asf(vy << 16);
                aw += asf(vy & 0xFFFF0000u);
            }
        }

        // combine the 4 quarter-wave partial sums
        ax += __shfl_xor(ax, 32); ay += __shfl_xor(ay, 32);
        az += __shfl_xor(az, 32); aw += __shfl_xor(aw, 32);
        ax += __shfl_xor(ax, 16); ay += __shfl_xor(ay, 16);
        az += __shfl_xor(az, 16); aw += __shfl_xor(aw, 16);

        // LayerNorm over 64 cols = 16 lanes x 4 comps
        float s = (ax + ay) + (az + aw);
#pragma unroll
        for (int o = 8; o > 0; o >>= 1) s += __shfl_xor(s, o);
        const float mu = s * (1.0f / D);
        const float dx = ax - mu, dy = ay - mu, dz = az - mu, dw = aw - mu;
        float s2 = (dx * dx + dy * dy) + (dz * dz + dw * dw);
#pragma unroll
        for (int o = 8; o > 0; o >>= 1) s2 += __shfl_xor(s2, o);
        const float rs = rsqrtf(s2 * (1.0f / D) + LN_EPS);

        if (lane < 16) {
            const float4 scv = *reinterpret_cast<const float4*>(sc + c * 4);
            const float4 biv = *reinterpret_cast<const float4*>(bi + c * 4);
            float4 o4;
            o4.x = dx * rs * scv.x + biv.x;
            o4.y = dy * rs * scv.y + biv.y;
            o4.z = dz * rs * scv.z + biv.z;
            o4.w = dw * rs * scv.w + biv.w;
            *reinterpret_cast<float4*>(out + (size_t)dst * D + c * 4) = o4;
        }
    }
}

// ---------------------------------------------------------------------------
extern "C" void kernel_launch(void* const* d_in, const int* in_sizes, int n_in,
                              void* d_out, int out_size, void* d_ws, size_t ws_size,
                              hipStream_t stream) {
    const float* feat = (const float*)d_in[0];
    const int*   esrc = (const int*)d_in[1];
    const int*   edst = (const int*)d_in[2];
    const float* Ww   = (const float*)d_in[3];
    const float* Fw   = (const float*)d_in[4];
    const float* sc   = (const float*)d_in[5];
    const float* bi   = (const float*)d_in[6];
    float* out = (float*)d_out;

    char* ws = (char*)d_ws;
    unsigned short* msgb = (unsigned short*)(ws);            // 12.8 MB bf16 msg
    unsigned* pairs  = (unsigned*)(ws + 26u * 1024 * 1024);  // 6.4 MB
    int*      H      = (int*)(ws + 33u * 1024 * 1024);       // 782*512*4 = 1.6 MB
    int*      bstart = (int*)(ws + 35u * 1024 * 1024);       // 783*4

    // 782 blocks x 128 rows = 100096 >= N_SRC
    k_film  <<<782, 256, 0, stream>>>(feat, Ww, Fw, msgb);
    k_hist1 <<<NCHUNK, 256, 0, stream>>>(edst, H);
    k_scanH <<<NBK, 512, 0, stream>>>(H, bstart);
    k_h3    <<<1, 64, 0, stream>>>(bstart);
    k_pairs <<<NCHUNK, 256, 0, stream>>>(esrc, edst, H, bstart, pairs);
    k_reduce2<<<NBK, 512, 0, stream>>>(msgb, pairs, bstart, sc, bi, out);
}

// Round 12
// 202.083 us; speedup vs baseline: 1.5914x; 1.0174x over previous
//
#include <hip/hip_runtime.h>

constexpr int N_SRC = 100000;
constexpr int N_DST = 100000;
constexpr int E     = 1600000;
constexpr int D     = 64;
constexpr float LN_EPS = 1e-5f;

constexpr int NCHUNK = 512;            // edge chunks
constexpr int CHUNK  = E / NCHUNK;     // 3125 edges per chunk (exact)
constexpr int BROWS  = 128;            // dst rows per bucket
constexpr int NBK    = (N_DST + BROWS - 1) / BROWS;   // 782 buckets
constexpr int MAXB   = 4096;           // per-bucket edge cap (mean 2046)
constexpr int FB     = 72;             // padded k-stride (ushorts) for weight LDS
constexpr int ZROW   = N_SRC;          // zeroed dummy msg row for tail lanes

typedef __attribute__((ext_vector_type(8))) short bf16x8;
typedef __attribute__((ext_vector_type(4))) float f32x4;

__device__ inline unsigned short bfh(float x) {
    union { float f; unsigned u; } c; c.f = x; return (unsigned short)(c.u >> 16);  // truncate
}
__device__ inline float bff(unsigned short b) {
    union { unsigned u; float f; } c; c.u = (unsigned)b << 16; return c.f;
}

// ---------------------------------------------------------------------------
// k_film v3: block = 128 rows (4 waves x 2 M-tiles). Weights split hi/lo once
// per block into padded LDS (coalesced staging: consecutive tids load
// consecutive n). Inner loop: 6 ds_read_b128 + 18 MFMA per (t,ks); 3-term
// split (hi*hi+hi*lo+lo*hi) ~ f32 accuracy. Epilogue: native f32 dword stores.
// ---------------------------------------------------------------------------
__global__ __launch_bounds__(256) void k_film(const float* __restrict__ feat,
                                              const float* __restrict__ Ww,   // [64][64]
                                              const float* __restrict__ Fw,   // [64][128]
                                              float* __restrict__ msg) {
    __shared__ unsigned short wl[6 * 64 * FB];   // 55296 B

    const int tid  = threadIdx.x;
    const int lane = tid & 63;
    const int wid  = tid >> 6;
    const int m    = lane & 15;
    const int kg   = lane >> 4;
    const int mrow0 = (blockIdx.x * 4 + wid) * 32;   // 32 rows per wave

    // ---- A fragments: 2 mtiles x 2 ksteps, hi/lo (registers) ----
    bf16x8 ahi[2][2], alo[2][2];
#pragma unroll
    for (int mt = 0; mt < 2; ++mt) {
        const int rbase = mrow0 + mt * 16 + m;
        const int r = (rbase < N_SRC) ? rbase : 0;
#pragma unroll
        for (int ks = 0; ks < 2; ++ks) {
            const float* p = feat + (size_t)r * 64 + ks * 32 + kg * 8;
            const float4 x0 = *reinterpret_cast<const float4*>(p);
            const float4 x1 = *reinterpret_cast<const float4*>(p + 4);
            const float a[8] = {x0.x, x0.y, x0.z, x0.w, x1.x, x1.y, x1.z, x1.w};
            bf16x8 h, l;
#pragma unroll
            for (int j = 0; j < 8; ++j) {
                const unsigned short hb = bfh(a[j]);
                h[j] = (short)hb;
                l[j] = (short)bfh(a[j] - bff(hb));
            }
            ahi[mt][ks] = h; alo[mt][ks] = l;
        }
    }

    // ---- weight split -> LDS, once per block (COALESCED: n = task & 63) ----
    for (int task = tid; task < 1536; task += 256) {
        const int n  = task & 63;
        const int g  = (task >> 6) & 7;
        const int mu = task >> 9;                 // 0=Wm, 1=gamma, 2=beta
        const float* src;
        int stride;
        if (mu == 0)      { src = Ww + n;       stride = 64;  }
        else if (mu == 1) { src = Fw + n;       stride = 128; }
        else              { src = Fw + 64 + n;  stride = 128; }
        bf16x8 h, l;
#pragma unroll
        for (int j = 0; j < 8; ++j) {
            const float v = src[(size_t)(8 * g + j) * stride];
            const unsigned short hb = bfh(v);
            h[j] = (short)hb;
            l[j] = (short)bfh(v - bff(hb));
        }
        *reinterpret_cast<bf16x8*>(&wl[(2 * mu + 0) * 64 * FB + n * FB + g * 8]) = h;
        *reinterpret_cast<bf16x8*>(&wl[(2 * mu + 1) * 64 * FB + n * FB + g * 8]) = l;
    }
    __syncthreads();

    const f32x4 zero = {0.f, 0.f, 0.f, 0.f};

#pragma unroll
    for (int t = 0; t < 4; ++t) {
        f32x4 am[2], ag[2], ab[2];
#pragma unroll
        for (int i = 0; i < 2; ++i) { am[i] = zero; ag[i] = zero; ab[i] = zero; }

#pragma unroll
        for (int ks = 0; ks < 2; ++ks) {
            const int n = t * 16 + m;
            const int base = n * FB + ks * 32 + kg * 8;
            const bf16x8 wmh = *reinterpret_cast<const bf16x8*>(&wl[0 * 64 * FB + base]);
            const bf16x8 wml = *reinterpret_cast<const bf16x8*>(&wl[1 * 64 * FB + base]);
            const bf16x8 wgh = *reinterpret_cast<const bf16x8*>(&wl[2 * 64 * FB + base]);
            const bf16x8 wgl = *reinterpret_cast<const bf16x8*>(&wl[3 * 64 * FB + base]);
            const bf16x8 wbh = *reinterpret_cast<const bf16x8*>(&wl[4 * 64 * FB + base]);
            const bf16x8 wbl = *reinterpret_cast<const bf16x8*>(&wl[5 * 64 * FB + base]);
#pragma unroll
            for (int mt = 0; mt < 2; ++mt) {
                am[mt] = __builtin_amdgcn_mfma_f32_16x16x32_bf16(ahi[mt][ks], wmh, am[mt], 0, 0, 0);
                am[mt] = __builtin_amdgcn_mfma_f32_16x16x32_bf16(ahi[mt][ks], wml, am[mt], 0, 0, 0);
                am[mt] = __builtin_amdgcn_mfma_f32_16x16x32_bf16(alo[mt][ks], wmh, am[mt], 0, 0, 0);
                ag[mt] = __builtin_amdgcn_mfma_f32_16x16x32_bf16(ahi[mt][ks], wgh, ag[mt], 0, 0, 0);
                ag[mt] = __builtin_amdgcn_mfma_f32_16x16x32_bf16(ahi[mt][ks], wgl, ag[mt], 0, 0, 0);
                ag[mt] = __builtin_amdgcn_mfma_f32_16x16x32_bf16(alo[mt][ks], wgh, ag[mt], 0, 0, 0);
                ab[mt] = __builtin_amdgcn_mfma_f32_16x16x32_bf16(ahi[mt][ks], wbh, ab[mt], 0, 0, 0);
                ab[mt] = __builtin_amdgcn_mfma_f32_16x16x32_bf16(ahi[mt][ks], wbl, ab[mt], 0, 0, 0);
                ab[mt] = __builtin_amdgcn_mfma_f32_16x16x32_bf16(alo[mt][ks], wbh, ab[mt], 0, 0, 0);
            }
        }

#pragma unroll
        for (int mt = 0; mt < 2; ++mt) {
            const int rb = mrow0 + mt * 16;
            if (rb < N_SRC) {      // N_SRC % 16 == 0: mtile all-or-nothing
#pragma unroll
                for (int r4 = 0; r4 < 4; ++r4) {
                    const int row = rb + kg * 4 + r4;
                    const float o = fmaxf(ag[mt][r4] * am[mt][r4] + ab[mt][r4], 0.f);
                    msg[(size_t)row * 64 + t * 16 + m] = o;   // native dword store
                }
            }
        }
    }
}

// ---------------------------------------------------------------------------
// Bucketed counting sort, all atomics in LDS.
// ---------------------------------------------------------------------------
__global__ __launch_bounds__(256) void k_hist1(const int* __restrict__ edst,
                                               int* __restrict__ H) {   // H[k][c]
    __shared__ int hl[NBK];
    for (int i = threadIdx.x; i < NBK; i += 256) hl[i] = 0;
    __syncthreads();
    const int c = blockIdx.x;
    const int e0 = c * CHUNK;
    for (int e = e0 + threadIdx.x; e < e0 + CHUNK; e += 256)
        atomicAdd(&hl[edst[e] >> 7], 1);
    __syncthreads();
    for (int i = threadIdx.x; i < NBK; i += 256) H[i * NCHUNK + c] = hl[i];
}

// one block (512 threads) per bucket: exclusive scan over 512 chunks
__global__ __launch_bounds__(512) void k_scanH(int* __restrict__ H,
                                               int* __restrict__ bstart) {
    const int k = blockIdx.x;
    const int c = threadIdx.x;
    const int lane = c & 63;
    const int wid = c >> 6;
    const int v = H[k * NCHUNK + c];
    int x = v;
#pragma unroll
    for (int o = 1; o < 64; o <<= 1) { int y = __shfl_up(x, o); if (lane >= o) x += y; }
    __shared__ int wsum[8];
    if (lane == 63) wsum[wid] = x;
    __syncthreads();
    int add = 0;
    for (int w = 0; w < wid; ++w) add += wsum[w];
    const int incl = x + add;
    H[k * NCHUNK + c] = incl - v;
    if (c == NCHUNK - 1) bstart[k] = incl;
}

__global__ __launch_bounds__(64) void k_h3(int* __restrict__ bstart) {
    const int lane = threadIdx.x;
    int running = 0;
    for (int b = 0; b < NBK; b += 64) {
        const int idx = b + lane;
        const int v = (idx < NBK) ? bstart[idx] : 0;
        int x = v;
#pragma unroll
        for (int o = 1; o < 64; o <<= 1) { int y = __shfl_up(x, o); if (lane >= o) x += y; }
        if (idx < NBK) bstart[idx] = running + x - v;
        running += __shfl(x, 63);
    }
    if (lane == 0) bstart[NBK] = E;
}

__global__ __launch_bounds__(256) void k_pairs(const int* __restrict__ esrc,
                                               const int* __restrict__ edst,
                                               const int* __restrict__ H,      // exclusive
                                               const int* __restrict__ bstart,
                                               unsigned* __restrict__ pairs) {
    __shared__ int curs[NBK];
    const int c = blockIdx.x;
    for (int i = threadIdx.x; i < NBK; i += 256) curs[i] = bstart[i] + H[i * NCHUNK + c];
    __syncthreads();
    const int e0 = c * CHUNK;
    for (int e = e0 + threadIdx.x; e < e0 + CHUNK; e += 256) {
        const int d = edst[e];
        const int s = esrc[e];
        const int k = d >> 7;
        const int pos = atomicAdd(&curs[k], 1);
        pairs[pos] = ((unsigned)(d & 127) << 24) | (unsigned)s;
    }
}

// ---------------------------------------------------------------------------
// k_reduce2 v3: 512 threads (8 waves) per bucket block; f32 msg.
//  Phase 1: LDS counting sort of src ids by row (int LDS atomics only).
//  Phase 2: wave per dst row, 16 rows/wave; lane=(q,c): float4 (4 cols),
//           4 edges per wave-gather, NATIVE dword gathers, no unpack VALU.
//           Tail lanes redirect to zeroed row ZROW (one cndmask, no masks).
//           shfl_xor merge; fused LN; lanes 0-15 store float4.
// ---------------------------------------------------------------------------
__global__ __launch_bounds__(512) void k_reduce2(const float* __restrict__ msg,
                                                 const unsigned* __restrict__ pairs,
                                                 const int* __restrict__ bstart,
                                                 const float* __restrict__ sc,
                                                 const float* __restrict__ bi,
                                                 float* __restrict__ out) {
    __shared__ int srcs[MAXB];      // 16 KB row-sorted src ids
    __shared__ int cnt[BROWS];
    __shared__ int off[BROWS];
    __shared__ int cur[BROWS];

    const int k = blockIdx.x;
    const int tid = threadIdx.x;
    const int lane = tid & 63;
    const int wid = tid >> 6;
    const int s0 = bstart[k];
    const int s1 = bstart[k + 1];

    for (int i = tid; i < BROWS; i += 512) cnt[i] = 0;
    __syncthreads();

    for (int i = s0 + tid; i < s1; i += 512) atomicAdd(&cnt[pairs[i] >> 24], 1);
    __syncthreads();

    if (tid < 64) {
        const int a = cnt[lane];
        const int b = cnt[64 + lane];
        int xa = a, xb = b;
#pragma unroll
        for (int o = 1; o < 64; o <<= 1) {
            int ya = __shfl_up(xa, o); if (lane >= o) xa += ya;
            int yb = __shfl_up(xb, o); if (lane >= o) xb += yb;
        }
        const int tot_a = __shfl(xa, 63);
        off[lane]      = xa - a;
        off[64 + lane] = tot_a + xb - b;
        cur[lane]      = off[lane];
        cur[64 + lane] = off[64 + lane];
    }
    __syncthreads();

    for (int i = s0 + tid; i < s1; i += 512) {
        const unsigned p = pairs[i];
        const int pos = atomicAdd(&cur[p >> 24], 1);
        if (pos < MAXB) srcs[pos] = (int)(p & 0x1FFFFu);
    }
    __syncthreads();

    const int q = lane >> 4;        // quarter-wave: which edge in group of 4
    const int c = lane & 15;        // 4-col group: cols 4c..4c+3

    for (int r = wid; r < BROWS; r += 8) {
        const int dst = k * BROWS + r;
        if (dst >= N_DST) break;
        const int rn = cnt[r];
        const int ro = off[r];

        float ax = 0.f, ay = 0.f, az = 0.f, aw = 0.f;
        for (int b0 = 0; b0 < rn; b0 += 32) {      // 32 edges per iter, 8 gathers
#pragma unroll
            for (int j = 0; j < 8; ++j) {
                if (b0 + 4 * j >= rn) break;          // wave-uniform early out
                const int ei = b0 + 4 * j + q;
                // LDS in-bounds: ei <= rn+2 <= bucket_total+2 < MAXB
                const int sj = (ei < rn) ? srcs[ro + ei] : ZROW;   // 1 cndmask
                const float4 v = *reinterpret_cast<const float4*>(
                    msg + (size_t)sj * D + c * 4);
                ax += v.x; ay += v.y; az += v.z; aw += v.w;
            }
        }

        // combine the 4 quarter-wave partial sums
        ax += __shfl_xor(ax, 32); ay += __shfl_xor(ay, 32);
        az += __shfl_xor(az, 32); aw += __shfl_xor(aw, 32);
        ax += __shfl_xor(ax, 16); ay += __shfl_xor(ay, 16);
        az += __shfl_xor(az, 16); aw += __shfl_xor(aw, 16);

        // LayerNorm over 64 cols = 16 lanes x 4 comps
        float s = (ax + ay) + (az + aw);
#pragma unroll
        for (int o = 8; o > 0; o >>= 1) s += __shfl_xor(s, o);
        const float mu = s * (1.0f / D);
        const float dx = ax - mu, dy = ay - mu, dz = az - mu, dw = aw - mu;
        float s2 = (dx * dx + dy * dy) + (dz * dz + dw * dw);
#pragma unroll
        for (int o = 8; o > 0; o >>= 1) s2 += __shfl_xor(s2, o);
        const float rs = rsqrtf(s2 * (1.0f / D) + LN_EPS);

        if (lane < 16) {
            const float4 scv = *reinterpret_cast<const float4*>(sc + c * 4);
            const float4 biv = *reinterpret_cast<const float4*>(bi + c * 4);
            float4 o4;
            o4.x = dx * rs * scv.x + biv.x;
            o4.y = dy * rs * scv.y + biv.y;
            o4.z = dz * rs * scv.z + biv.z;
            o4.w = dw * rs * scv.w + biv.w;
            *reinterpret_cast<float4*>(out + (size_t)dst * D + c * 4) = o4;
        }
    }
}

// ---------------------------------------------------------------------------
extern "C" void kernel_launch(void* const* d_in, const int* in_sizes, int n_in,
                              void* d_out, int out_size, void* d_ws, size_t ws_size,
                              hipStream_t stream) {
    const float* feat = (const float*)d_in[0];
    const int*   esrc = (const int*)d_in[1];
    const int*   edst = (const int*)d_in[2];
    const float* Ww   = (const float*)d_in[3];
    const float* Fw   = (const float*)d_in[4];
    const float* sc   = (const float*)d_in[5];
    const float* bi   = (const float*)d_in[6];
    float* out = (float*)d_out;

    char* ws = (char*)d_ws;
    float*    msg    = (float*)(ws);                         // (100001 rows) 25.6 MB
    unsigned* pairs  = (unsigned*)(ws + 26u * 1024 * 1024);  // 6.4 MB
    int*      H      = (int*)(ws + 33u * 1024 * 1024);       // 782*512*4 = 1.6 MB
    int*      bstart = (int*)(ws + 35u * 1024 * 1024);       // 783*4

    // zero the dummy tail row once per call (ws is re-poisoned each launch)
    hipMemsetAsync(msg + (size_t)ZROW * D, 0, D * sizeof(float), stream);

    // 782 blocks x 128 rows = 100096 >= N_SRC
    k_film  <<<782, 256, 0, stream>>>(feat, Ww, Fw, msg);
    k_hist1 <<<NCHUNK, 256, 0, stream>>>(edst, H);
    k_scanH <<<NBK, 512, 0, stream>>>(H, bstart);
    k_h3    <<<1, 64, 0, stream>>>(bstart);
    k_pairs <<<NCHUNK, 256, 0, stream>>>(esrc, edst, H, bstart, pairs);
    k_reduce2<<<NBK, 512, 0, stream>>>(msg, pairs, bstart, sc, bi, out);
}